// Round 4
// baseline (156.200 us; speedup 1.0000x reference)
//
#include <hip/hip_runtime.h>
#include <hip/hip_bf16.h>

#define NROWS 16384
#define DDIM  256
#define LOG2E 1.4426950408889634f
#define SCALE 7.213475204444817f   // (1/tau) * log2(e), tau = 0.2

typedef __attribute__((ext_vector_type(8))) short short8;
typedef __attribute__((ext_vector_type(4))) float f32x4;

__device__ __forceinline__ unsigned short f2bf_rne(float f) {
  union { float f; unsigned int u; } v; v.f = f;
  unsigned int u = v.u;
  return (unsigned short)((u + 0x7FFFu + ((u >> 16) & 1u)) >> 16);
}

// ---------------------------------------------------------------------------
// Kernel 1: L2-normalize rows of z1,z2 -> bf16 h1,h2; exact fp32 diag logits
// (diag5[i] = 5 * cos(z1_i, z2_i)); zero rowsum. One wave per row.
// ---------------------------------------------------------------------------
__global__ __launch_bounds__(256) void prep_kernel(
    const float* __restrict__ z1, const float* __restrict__ z2,
    ushort* __restrict__ h1, ushort* __restrict__ h2,
    float* __restrict__ diag5, float* __restrict__ rowsum) {
  int tid = threadIdx.x;
  int w = tid >> 6, lane = tid & 63;
  int r = blockIdx.x * 4 + w;

  const float4 a = ((const float4*)z1)[r * 64 + lane];
  const float4 b = ((const float4*)z2)[r * 64 + lane];

  float ss1 = a.x * a.x + a.y * a.y + a.z * a.z + a.w * a.w;
  float ss2 = b.x * b.x + b.y * b.y + b.z * b.z + b.w * b.w;
  float dp  = a.x * b.x + a.y * b.y + a.z * b.z + a.w * b.w;
  #pragma unroll
  for (int m = 1; m <= 32; m <<= 1) {
    ss1 += __shfl_xor(ss1, m);
    ss2 += __shfl_xor(ss2, m);
    dp  += __shfl_xor(dp, m);
  }
  float inv1 = 1.0f / fmaxf(sqrtf(ss1), 1e-12f);
  float inv2 = 1.0f / fmaxf(sqrtf(ss2), 1e-12f);

  ushort4 o1, o2;
  o1.x = f2bf_rne(a.x * inv1); o1.y = f2bf_rne(a.y * inv1);
  o1.z = f2bf_rne(a.z * inv1); o1.w = f2bf_rne(a.w * inv1);
  o2.x = f2bf_rne(b.x * inv2); o2.y = f2bf_rne(b.y * inv2);
  o2.z = f2bf_rne(b.z * inv2); o2.w = f2bf_rne(b.w * inv2);
  ((ushort4*)h1)[r * 64 + lane] = o1;
  ((ushort4*)h2)[r * 64 + lane] = o2;

  if (lane == 0) diag5[r] = dp * inv1 * inv2 * 5.0f;
  if (tid < 4) rowsum[blockIdx.x * 4 + tid] = 0.0f;  // 4096 blocks * 4 = 16384
}

// ---------------------------------------------------------------------------
// Kernel 2: rowsum_i = sum_j exp(sim_ij / tau) via bf16 MFMA.
// Block = 256 thr (4 waves), Mw=64 rows/wave -> BM=256 rows/block.
// 8-way column split -> grid = 64 row-blocks * 8 = 512 blocks = 2 blocks/CU.
// m=4: each 1KB B-fragment (ds_read_b128) feeds 4 MFMAs -> LDS-read pipe
// (8192 reads/CU * ~16cyc = 55us) drops below the MFMA pipe (66us).
// A fragments afr[4][8] = 128 VGPR held resident: amdgpu_waves_per_eu(2,2)
// gives the allocator a 256-VGPR budget (2 waves/EU = 8 waves/CU = exactly
// the 2-block LDS residency), so no spill/remat (rounds 2-3 failure mode).
// h2 tiles (64 cols x 256 k) double-buffered in LDS via
// global_load_lds(width=16), XOR-swizzled source + same XOR on read.
// ---------------------------------------------------------------------------
#define CSPL 8
#define BN   64
#define NJT  ((NROWS / CSPL) / BN)   // 32 j-tiles per block

__global__ __launch_bounds__(256)
__attribute__((amdgpu_waves_per_eu(2, 2)))
void simexp_kernel(
    const ushort* __restrict__ h1, const ushort* __restrict__ h2,
    float* __restrict__ rowsum) {
  __shared__ alignas(16) ushort lds[2][BN * DDIM];   // 2 x 32 KB

  int tid = threadIdx.x, w = tid >> 6, lane = tid & 63;
  int bx = blockIdx.x;
  int rb = bx >> 3;        // row block 0..63 (256 rows each)
  int cs = bx & 7;         // column split 0..7 == default XCD id (L2 locality)
  int row0 = rb * 256 + w * 64;
  int c0 = cs * (NROWS / CSPL);

  const char* h1b = (const char*)h1;
  const char* h2b = (const char*)h2;

  // A fragments: 4 row-subtiles x 8 k-steps, 8 bf16 each -> 128 VGPRs, resident
  short8 afr[4][8];
  #pragma unroll
  for (int m = 0; m < 4; ++m)
    #pragma unroll
    for (int ks = 0; ks < 8; ++ks) {
      int row = row0 + m * 16 + (lane & 15);
      int off = row * 512 + ks * 64 + (lane >> 4) * 16;
      afr[m][ks] = *reinterpret_cast<const short8*>(h1b + off);
    }

  float rs[4][4];
  #pragma unroll
  for (int m = 0; m < 4; ++m)
    #pragma unroll
    for (int r = 0; r < 4; ++r) rs[m][r] = 0.0f;

  // stage one 64x256 bf16 h2 tile: wave w stages rows w*16..w*16+15 (8 instrs)
  auto stage = [&](int buf, int jt) {
    int j0 = c0 + jt * BN;
    int rbase = w * 16;
    #pragma unroll
    for (int i = 0; i < 8; ++i) {
      int rit = rbase + i * 2 + (lane >> 5);         // row in tile 0..63
      int kb  = (lane & 31) * 16;                    // byte offset in row
      int src = (j0 + rit) * 512 + (kb ^ ((rit & 7) << 4));  // pre-swizzled src
      __builtin_amdgcn_global_load_lds(
          (const __attribute__((address_space(1))) void*)(h2b + src),
          (__attribute__((address_space(3))) void*)&lds[buf][(rbase + i * 2) * DDIM],
          16, 0, 0);
    }
  };

  stage(0, 0);
  __syncthreads();

  for (int jt = 0; jt < NJT; ++jt) {
    int cur = jt & 1;
    if (jt + 1 < NJT) stage(cur ^ 1, jt + 1);

    const char* L = (const char*)lds[cur];
    #pragma unroll
    for (int n = 0; n < 4; ++n) {
      f32x4 acc[4];
      #pragma unroll
      for (int m = 0; m < 4; ++m) acc[m] = (f32x4){0.f, 0.f, 0.f, 0.f};

      #pragma unroll
      for (int ks = 0; ks < 8; ++ks) {
        int row = n * 16 + (lane & 15);
        int kb  = ks * 64 + (lane >> 4) * 16;
        int off = row * 512 + (kb ^ ((row & 7) << 4));   // same involution as stage
        short8 bfr = *reinterpret_cast<const short8*>(L + off);
        #pragma unroll
        for (int m = 0; m < 4; ++m)
          acc[m] = __builtin_amdgcn_mfma_f32_16x16x32_bf16(afr[m][ks], bfr, acc[m], 0, 0, 0);
      }
      // exp(sim/tau) = exp2(sim * SCALE); accumulate row partial sums
      #pragma unroll
      for (int m = 0; m < 4; ++m)
        #pragma unroll
        for (int r = 0; r < 4; ++r)
          rs[m][r] += __builtin_amdgcn_exp2f(acc[m][r] * SCALE);
    }
    __syncthreads();
  }

  // reduce the 16 column-lanes (lane&15) and add to global rowsum
  #pragma unroll
  for (int m = 0; m < 4; ++m)
    #pragma unroll
    for (int r = 0; r < 4; ++r) {
      float v = rs[m][r];
      v += __shfl_xor(v, 1);
      v += __shfl_xor(v, 2);
      v += __shfl_xor(v, 4);
      v += __shfl_xor(v, 8);
      if ((lane & 15) == 0)
        atomicAdd(&rowsum[row0 + m * 16 + (lane >> 4) * 4 + r], v);
    }
}

// ---------------------------------------------------------------------------
// Kernel 3: loss = sum_i [ log(rowsum_i - exp(diag5_i)) - diag5_i ]
// ---------------------------------------------------------------------------
__global__ __launch_bounds__(1024) void loss_kernel(
    const float* __restrict__ rowsum, const float* __restrict__ diag5,
    float* __restrict__ out) {
  int tid = threadIdx.x;
  float s = 0.0f;
  for (int i = tid; i < NROWS; i += 1024) {
    float d5 = diag5[i];
    float de = __builtin_amdgcn_exp2f(d5 * LOG2E);
    s += logf(rowsum[i] - de) - d5;
  }
  #pragma unroll
  for (int m = 1; m <= 32; m <<= 1) s += __shfl_xor(s, m);
  __shared__ float wsum[16];
  if ((tid & 63) == 0) wsum[tid >> 6] = s;
  __syncthreads();
  if (tid == 0) {
    float t = 0.0f;
    #pragma unroll
    for (int i = 0; i < 16; ++i) t += wsum[i];
    out[0] = t;
  }
}

// ---------------------------------------------------------------------------
extern "C" void kernel_launch(void* const* d_in, const int* in_sizes, int n_in,
                              void* d_out, int out_size, void* d_ws, size_t ws_size,
                              hipStream_t stream) {
  const float* z1 = (const float*)d_in[0];
  const float* z2 = (const float*)d_in[1];

  char* ws = (char*)d_ws;
  ushort* h1    = (ushort*)(ws);               // 16384*256*2 = 8388608 B
  ushort* h2    = (ushort*)(ws + 8388608);     // 8388608 B
  float*  diag5 = (float*)(ws + 16777216);     // 65536 B
  float*  rowsm = (float*)(ws + 16842752);     // 65536 B
  if (ws_size < 16908288) return;              // fail loudly (poison stays)

  prep_kernel<<<4096, 256, 0, stream>>>(z1, z2, h1, h2, diag5, rowsm);
  simexp_kernel<<<512, 256, 0, stream>>>(h1, h2, rowsm);
  loss_kernel<<<1, 1024, 0, stream>>>(rowsm, diag5, (float*)d_out);
}

// Round 5
// 155.826 us; speedup vs baseline: 1.0024x; 1.0024x over previous
//
#include <hip/hip_runtime.h>
#include <hip/hip_bf16.h>

#define NROWS 16384
#define DDIM  256
#define LOG2E 1.4426950408889634f
#define SCALE 7.213475204444817f   // (1/tau) * log2(e), tau = 0.2

typedef __attribute__((ext_vector_type(8))) short short8;
typedef __attribute__((ext_vector_type(4))) float f32x4;

__device__ __forceinline__ unsigned short f2bf_rne(float f) {
  union { float f; unsigned int u; } v; v.f = f;
  unsigned int u = v.u;
  return (unsigned short)((u + 0x7FFFu + ((u >> 16) & 1u)) >> 16);
}

// ---------------------------------------------------------------------------
// Kernel 1: L2-normalize rows of z1,z2 -> bf16 h1,h2; exact fp32 diag logits
// (diag5[i] = 5 * cos(z1_i, z2_i)); zero rowsum. One wave per row.
// ---------------------------------------------------------------------------
__global__ __launch_bounds__(256) void prep_kernel(
    const float* __restrict__ z1, const float* __restrict__ z2,
    ushort* __restrict__ h1, ushort* __restrict__ h2,
    float* __restrict__ diag5, float* __restrict__ rowsum) {
  int tid = threadIdx.x;
  int w = tid >> 6, lane = tid & 63;
  int r = blockIdx.x * 4 + w;

  const float4 a = ((const float4*)z1)[r * 64 + lane];
  const float4 b = ((const float4*)z2)[r * 64 + lane];

  float ss1 = a.x * a.x + a.y * a.y + a.z * a.z + a.w * a.w;
  float ss2 = b.x * b.x + b.y * b.y + b.z * b.z + b.w * b.w;
  float dp  = a.x * b.x + a.y * b.y + a.z * b.z + a.w * b.w;
  #pragma unroll
  for (int m = 1; m <= 32; m <<= 1) {
    ss1 += __shfl_xor(ss1, m);
    ss2 += __shfl_xor(ss2, m);
    dp  += __shfl_xor(dp, m);
  }
  float inv1 = 1.0f / fmaxf(sqrtf(ss1), 1e-12f);
  float inv2 = 1.0f / fmaxf(sqrtf(ss2), 1e-12f);

  ushort4 o1, o2;
  o1.x = f2bf_rne(a.x * inv1); o1.y = f2bf_rne(a.y * inv1);
  o1.z = f2bf_rne(a.z * inv1); o1.w = f2bf_rne(a.w * inv1);
  o2.x = f2bf_rne(b.x * inv2); o2.y = f2bf_rne(b.y * inv2);
  o2.z = f2bf_rne(b.z * inv2); o2.w = f2bf_rne(b.w * inv2);
  ((ushort4*)h1)[r * 64 + lane] = o1;
  ((ushort4*)h2)[r * 64 + lane] = o2;

  if (lane == 0) diag5[r] = dp * inv1 * inv2 * 5.0f;
  if (tid < 4) rowsum[blockIdx.x * 4 + tid] = 0.0f;  // 4096 blocks * 4 = 16384
}

// ---------------------------------------------------------------------------
// Kernel 2: rowsum_i = sum_j exp(sim_ij / tau) via bf16 MFMA.
// Block = 256 thr (4 waves), Mw=64 rows/wave -> BM=256 rows/block.
// 8-way column split -> grid = 64 row-blocks * 8 = 512 blocks = 2 blocks/CU.
// Pipe model per CU per j-tile: MFMA 1024*4.85=4966 cyc (binding), LDS reads
// 256KB/128Bcyc=2000 cyc, L2 fetch 64KB=13 B/cyc -> MFMA-bound if stalls gone.
// afr[4][8] (128 VGPR) is pinned live via empty asm "+v" after the load:
// rounds 1-4 showed the allocator otherwise REMATERIALIZES these global loads
// inside the j-loop (VGPR squeezed to 64/128, ~200cyc L2 reloads in the inner
// loop -> MfmaUtil capped at 38-50%). amdgpu_waves_per_eu(2,2) gives the
// 256-VGPR budget (8 waves/CU = exactly the 2-block LDS residency).
// h2 tiles (64 cols x 256 k) double-buffered in LDS via
// global_load_lds(width=16), XOR-swizzled source + same XOR on read.
// ---------------------------------------------------------------------------
#define CSPL 8
#define BN   64
#define NJT  ((NROWS / CSPL) / BN)   // 32 j-tiles per block

__global__ __launch_bounds__(256)
__attribute__((amdgpu_waves_per_eu(2, 2)))
void simexp_kernel(
    const ushort* __restrict__ h1, const ushort* __restrict__ h2,
    float* __restrict__ rowsum) {
  __shared__ alignas(16) ushort lds[2][BN * DDIM];   // 2 x 32 KB

  int tid = threadIdx.x, w = tid >> 6, lane = tid & 63;
  int bx = blockIdx.x;
  int rb = bx >> 3;        // row block 0..63 (256 rows each)
  int cs = bx & 7;         // column split 0..7 == default XCD id (L2 locality)
  int row0 = rb * 256 + w * 64;
  int c0 = cs * (NROWS / CSPL);

  const char* h1b = (const char*)h1;
  const char* h2b = (const char*)h2;

  // A fragments: 4 row-subtiles x 8 k-steps, 8 bf16 each -> 128 VGPRs
  short8 afr[4][8];
  #pragma unroll
  for (int m = 0; m < 4; ++m)
    #pragma unroll
    for (int ks = 0; ks < 8; ++ks) {
      int row = row0 + m * 16 + (lane & 15);
      int off = row * 512 + ks * 64 + (lane >> 4) * 16;
      afr[m][ks] = *reinterpret_cast<const short8*>(h1b + off);
    }
  // Pin: make each fragment opaque so the allocator cannot rematerialize the
  // global load inside the j-loop (the round-2/3/4 failure mode).
  #pragma unroll
  for (int m = 0; m < 4; ++m)
    #pragma unroll
    for (int ks = 0; ks < 8; ++ks)
      asm volatile("" : "+v"(afr[m][ks]));

  float rs[4][4];
  #pragma unroll
  for (int m = 0; m < 4; ++m)
    #pragma unroll
    for (int r = 0; r < 4; ++r) rs[m][r] = 0.0f;

  // stage one 64x256 bf16 h2 tile: wave w stages rows w*16..w*16+15 (8 instrs)
  auto stage = [&](int buf, int jt) {
    int j0 = c0 + jt * BN;
    int rbase = w * 16;
    #pragma unroll
    for (int i = 0; i < 8; ++i) {
      int rit = rbase + i * 2 + (lane >> 5);         // row in tile 0..63
      int kb  = (lane & 31) * 16;                    // byte offset in row
      int src = (j0 + rit) * 512 + (kb ^ ((rit & 7) << 4));  // pre-swizzled src
      __builtin_amdgcn_global_load_lds(
          (const __attribute__((address_space(1))) void*)(h2b + src),
          (__attribute__((address_space(3))) void*)&lds[buf][(rbase + i * 2) * DDIM],
          16, 0, 0);
    }
  };

  stage(0, 0);
  __syncthreads();

  for (int jt = 0; jt < NJT; ++jt) {
    int cur = jt & 1;
    if (jt + 1 < NJT) stage(cur ^ 1, jt + 1);

    const char* L = (const char*)lds[cur];
    #pragma unroll
    for (int n = 0; n < 4; ++n) {
      f32x4 acc[4];
      #pragma unroll
      for (int m = 0; m < 4; ++m) acc[m] = (f32x4){0.f, 0.f, 0.f, 0.f};

      #pragma unroll
      for (int ks = 0; ks < 8; ++ks) {
        int row = n * 16 + (lane & 15);
        int kb  = ks * 64 + (lane >> 4) * 16;
        int off = row * 512 + (kb ^ ((row & 7) << 4));   // same involution as stage
        short8 bfr = *reinterpret_cast<const short8*>(L + off);
        #pragma unroll
        for (int m = 0; m < 4; ++m)
          acc[m] = __builtin_amdgcn_mfma_f32_16x16x32_bf16(afr[m][ks], bfr, acc[m], 0, 0, 0);
      }
      // exp(sim/tau) = exp2(sim * SCALE); accumulate row partial sums
      #pragma unroll
      for (int m = 0; m < 4; ++m)
        #pragma unroll
        for (int r = 0; r < 4; ++r)
          rs[m][r] += __builtin_amdgcn_exp2f(acc[m][r] * SCALE);
    }
    __syncthreads();
  }

  // reduce the 16 column-lanes (lane&15) and add to global rowsum
  #pragma unroll
  for (int m = 0; m < 4; ++m)
    #pragma unroll
    for (int r = 0; r < 4; ++r) {
      float v = rs[m][r];
      v += __shfl_xor(v, 1);
      v += __shfl_xor(v, 2);
      v += __shfl_xor(v, 4);
      v += __shfl_xor(v, 8);
      if ((lane & 15) == 0)
        atomicAdd(&rowsum[row0 + m * 16 + (lane >> 4) * 4 + r], v);
    }
}

// ---------------------------------------------------------------------------
// Kernel 3: loss = sum_i [ log(rowsum_i - exp(diag5_i)) - diag5_i ]
// ---------------------------------------------------------------------------
__global__ __launch_bounds__(1024) void loss_kernel(
    const float* __restrict__ rowsum, const float* __restrict__ diag5,
    float* __restrict__ out) {
  int tid = threadIdx.x;
  float s = 0.0f;
  for (int i = tid; i < NROWS; i += 1024) {
    float d5 = diag5[i];
    float de = __builtin_amdgcn_exp2f(d5 * LOG2E);
    s += logf(rowsum[i] - de) - d5;
  }
  #pragma unroll
  for (int m = 1; m <= 32; m <<= 1) s += __shfl_xor(s, m);
  __shared__ float wsum[16];
  if ((tid & 63) == 0) wsum[tid >> 6] = s;
  __syncthreads();
  if (tid == 0) {
    float t = 0.0f;
    #pragma unroll
    for (int i = 0; i < 16; ++i) t += wsum[i];
    out[0] = t;
  }
}

// ---------------------------------------------------------------------------
extern "C" void kernel_launch(void* const* d_in, const int* in_sizes, int n_in,
                              void* d_out, int out_size, void* d_ws, size_t ws_size,
                              hipStream_t stream) {
  const float* z1 = (const float*)d_in[0];
  const float* z2 = (const float*)d_in[1];

  char* ws = (char*)d_ws;
  ushort* h1    = (ushort*)(ws);               // 16384*256*2 = 8388608 B
  ushort* h2    = (ushort*)(ws + 8388608);     // 8388608 B
  float*  diag5 = (float*)(ws + 16777216);     // 65536 B
  float*  rowsm = (float*)(ws + 16842752);     // 65536 B
  if (ws_size < 16908288) return;              // fail loudly (poison stays)

  prep_kernel<<<4096, 256, 0, stream>>>(z1, z2, h1, h2, diag5, rowsm);
  simexp_kernel<<<512, 256, 0, stream>>>(h1, h2, rowsm);
  loss_kernel<<<1, 1024, 0, stream>>>(rowsm, diag5, (float*)d_out);
}

// Round 6
// 114.939 us; speedup vs baseline: 1.3590x; 1.3557x over previous
//
#include <hip/hip_runtime.h>
#include <hip/hip_bf16.h>

#define NROWS 16384
#define DDIM  256
#define LOG2E 1.4426950408889634f
#define SCALE 7.213475204444817f   // (1/tau) * log2(e), tau = 0.2

typedef __attribute__((ext_vector_type(4))) float f32x4;
typedef long long i64t;

// ---------------------------------------------------------------------------
// Kernel 1: L2-normalize rows of z1,z2; quantize to OCP fp8 e4m3:
//   h1q = fp8(SCALE * h1_norm)   (A side, pre-scaled so exp2(acc) is direct)
//   h2q = fp8(h2_norm)           (B side)
// exact fp32 diag logits diag5[i] = 5 * cos(z1_i, z2_i); zero rowsum.
// One wave per row; lane packs its 4 floats via v_cvt_pk_fp8_f32.
// ---------------------------------------------------------------------------
__global__ __launch_bounds__(256) void prep_kernel(
    const float* __restrict__ z1, const float* __restrict__ z2,
    unsigned char* __restrict__ h1q, unsigned char* __restrict__ h2q,
    float* __restrict__ diag5, float* __restrict__ rowsum) {
  int tid = threadIdx.x;
  int w = tid >> 6, lane = tid & 63;
  int r = blockIdx.x * 4 + w;

  const float4 a = ((const float4*)z1)[r * 64 + lane];
  const float4 b = ((const float4*)z2)[r * 64 + lane];

  float ss1 = a.x * a.x + a.y * a.y + a.z * a.z + a.w * a.w;
  float ss2 = b.x * b.x + b.y * b.y + b.z * b.z + b.w * b.w;
  float dp  = a.x * b.x + a.y * b.y + a.z * b.z + a.w * b.w;
  #pragma unroll
  for (int m = 1; m <= 32; m <<= 1) {
    ss1 += __shfl_xor(ss1, m);
    ss2 += __shfl_xor(ss2, m);
    dp  += __shfl_xor(dp, m);
  }
  float inv1 = 1.0f / fmaxf(sqrtf(ss1), 1e-12f);
  float inv2 = 1.0f / fmaxf(sqrtf(ss2), 1e-12f);
  float s1 = inv1 * SCALE;         // fold 1/tau*log2e into A

  int p1 = __builtin_amdgcn_cvt_pk_fp8_f32(a.x * s1, a.y * s1, 0, false);
  p1     = __builtin_amdgcn_cvt_pk_fp8_f32(a.z * s1, a.w * s1, p1, true);
  int p2 = __builtin_amdgcn_cvt_pk_fp8_f32(b.x * inv2, b.y * inv2, 0, false);
  p2     = __builtin_amdgcn_cvt_pk_fp8_f32(b.z * inv2, b.w * inv2, p2, true);
  ((int*)h1q)[r * 64 + lane] = p1;
  ((int*)h2q)[r * 64 + lane] = p2;

  if (lane == 0) diag5[r] = dp * inv1 * inv2 * 5.0f;
  if (tid < 4) rowsum[blockIdx.x * 4 + tid] = 0.0f;  // 4096 blocks * 4 = 16384
}

// ---------------------------------------------------------------------------
// Kernel 2: rowsum_i = sum_j exp2(h1q_i . h2q_j) via fp8 MFMA (e4m3, i64 ops).
// Block = 256 thr (4 waves), Mw=64 rows/wave -> BM=256 rows/block.
// 16-way column split -> grid = 64*16 = 1024 blocks = 4 blocks/CU
// (LDS 4*32KB=128<=160; VGPR<=128 -> 16 waves/CU).
// fp8 halves the A-fragment file: afr[4][8] i64 = 64 VGPR; total demand
// ~115 < the 128 cliff -> no remat (the r1-r5 failure mode).
// Pipes per CU: MFMA 32768*4.85 = 66us (binding); LDS reads (fp8, b64)
// ~20us; trans/VALU ~35us -> MFMA-bound with 16 waves of TLP.
// h2q tiles (64 cols x 256 k fp8 = 16KB) double-buffered via
// global_load_lds(width=16), XOR-swizzled source + same XOR on read.
// ---------------------------------------------------------------------------
#define CSPL 16
#define BN   64
#define NJT  ((NROWS / CSPL) / BN)   // 16 j-tiles per block

__global__ __launch_bounds__(256) void simexp_kernel(
    const unsigned char* __restrict__ h1q, const unsigned char* __restrict__ h2q,
    float* __restrict__ rowsum) {
  __shared__ alignas(16) unsigned char lds[2][BN * DDIM];   // 2 x 16 KB

  int tid = threadIdx.x, w = tid >> 6, lane = tid & 63;
  int bx = blockIdx.x;
  int rb = bx >> 4;        // row block 0..63 (256 rows each)
  int cs = bx & 15;        // column split 0..15 (cs, cs+8 share an XCD L2)
  int row0 = rb * 256 + w * 64;
  int c0 = cs * (NROWS / CSPL);

  const char* h1b = (const char*)h1q;
  const char* h2b = (const char*)h2q;

  // A fragments: 4 row-subtiles x 8 k-steps, 8 fp8 each -> 64 VGPRs, resident
  i64t afr[4][8];
  #pragma unroll
  for (int m = 0; m < 4; ++m)
    #pragma unroll
    for (int ks = 0; ks < 8; ++ks) {
      int row = row0 + m * 16 + (lane & 15);
      int off = row * 256 + ks * 32 + (lane >> 4) * 8;
      afr[m][ks] = *reinterpret_cast<const i64t*>(h1b + off);
    }
  #pragma unroll
  for (int m = 0; m < 4; ++m)
    #pragma unroll
    for (int ks = 0; ks < 8; ++ks)
      asm volatile("" : "+v"(afr[m][ks]));   // keep resident (fits: ~115 regs)

  float rs[4][4];
  #pragma unroll
  for (int m = 0; m < 4; ++m)
    #pragma unroll
    for (int r = 0; r < 4; ++r) rs[m][r] = 0.0f;

  // stage one 64x256 fp8 h2 tile (16 KB): wave w stages rows w*16..w*16+15
  auto stage = [&](int buf, int jt) {
    int j0 = c0 + jt * BN;
    int rbase = w * 16;
    #pragma unroll
    for (int i = 0; i < 4; ++i) {
      int rit = rbase + i * 4 + (lane >> 4);         // row in tile 0..63
      int kb  = (lane & 15) * 16;                    // byte offset in row
      int src = (j0 + rit) * 256 + (kb ^ ((rit & 7) << 4));  // pre-swizzled src
      __builtin_amdgcn_global_load_lds(
          (const __attribute__((address_space(1))) void*)(h2b + src),
          (__attribute__((address_space(3))) void*)&lds[buf][(rbase + i * 4) * DDIM],
          16, 0, 0);
    }
  };

  stage(0, 0);
  __syncthreads();

  for (int jt = 0; jt < NJT; ++jt) {
    int cur = jt & 1;
    if (jt + 1 < NJT) stage(cur ^ 1, jt + 1);

    const char* L = (const char*)lds[cur];
    #pragma unroll
    for (int n = 0; n < 4; ++n) {
      f32x4 acc[4];
      #pragma unroll
      for (int m = 0; m < 4; ++m) acc[m] = (f32x4){0.f, 0.f, 0.f, 0.f};

      #pragma unroll
      for (int ks = 0; ks < 8; ++ks) {
        int row = n * 16 + (lane & 15);
        int kb  = ks * 32 + (lane >> 4) * 8;
        int off = row * 256 + (kb ^ ((row & 7) << 4));   // same involution as stage
        i64t bfr = *reinterpret_cast<const i64t*>(L + off);
        #pragma unroll
        for (int m = 0; m < 4; ++m)
          acc[m] = __builtin_amdgcn_mfma_f32_16x16x32_fp8_fp8(afr[m][ks], bfr, acc[m], 0, 0, 0);
      }
      // A was pre-scaled by (1/tau)*log2e -> rowsum term = exp2(acc) directly
      #pragma unroll
      for (int m = 0; m < 4; ++m)
        #pragma unroll
        for (int r = 0; r < 4; ++r)
          rs[m][r] += __builtin_amdgcn_exp2f(acc[m][r]);
    }
    __syncthreads();
  }

  // reduce the 16 column-lanes (lane&15) and add to global rowsum
  #pragma unroll
  for (int m = 0; m < 4; ++m)
    #pragma unroll
    for (int r = 0; r < 4; ++r) {
      float v = rs[m][r];
      v += __shfl_xor(v, 1);
      v += __shfl_xor(v, 2);
      v += __shfl_xor(v, 4);
      v += __shfl_xor(v, 8);
      if ((lane & 15) == 0)
        atomicAdd(&rowsum[row0 + m * 16 + (lane >> 4) * 4 + r], v);
    }
}

// ---------------------------------------------------------------------------
// Kernel 3: loss = sum_i [ log(rowsum_i - exp(diag5_i)) - diag5_i ]
// ---------------------------------------------------------------------------
__global__ __launch_bounds__(1024) void loss_kernel(
    const float* __restrict__ rowsum, const float* __restrict__ diag5,
    float* __restrict__ out) {
  int tid = threadIdx.x;
  float s = 0.0f;
  for (int i = tid; i < NROWS; i += 1024) {
    float d5 = diag5[i];
    float de = __builtin_amdgcn_exp2f(d5 * LOG2E);
    s += logf(rowsum[i] - de) - d5;
  }
  #pragma unroll
  for (int m = 1; m <= 32; m <<= 1) s += __shfl_xor(s, m);
  __shared__ float wsum[16];
  if ((tid & 63) == 0) wsum[tid >> 6] = s;
  __syncthreads();
  if (tid == 0) {
    float t = 0.0f;
    #pragma unroll
    for (int i = 0; i < 16; ++i) t += wsum[i];
    out[0] = t;
  }
}

// ---------------------------------------------------------------------------
extern "C" void kernel_launch(void* const* d_in, const int* in_sizes, int n_in,
                              void* d_out, int out_size, void* d_ws, size_t ws_size,
                              hipStream_t stream) {
  const float* z1 = (const float*)d_in[0];
  const float* z2 = (const float*)d_in[1];

  char* ws = (char*)d_ws;
  unsigned char* h1q = (unsigned char*)(ws);             // 16384*256 = 4 MB
  unsigned char* h2q = (unsigned char*)(ws + 4194304);   // 4 MB
  float* diag5 = (float*)(ws + 8388608);                 // 64 KB
  float* rowsm = (float*)(ws + 8454144);                 // 64 KB
  if (ws_size < 8519680) return;                         // fail loudly

  prep_kernel<<<4096, 256, 0, stream>>>(z1, z2, h1q, h2q, diag5, rowsm);
  simexp_kernel<<<1024, 256, 0, stream>>>(h1q, h2q, rowsm);
  loss_kernel<<<1, 1024, 0, stream>>>(rowsm, diag5, (float*)d_out);
}

// Round 7
// 86.526 us; speedup vs baseline: 1.8052x; 1.3284x over previous
//
#include <hip/hip_runtime.h>
#include <hip/hip_bf16.h>

#define NROWS 16384
#define DDIM  256
#define LOG2E 1.4426950408889634f
#define SCALE 7.213475204444817f   // (1/tau) * log2(e), tau = 0.2

typedef __attribute__((ext_vector_type(4))) float f32x4;
typedef __attribute__((ext_vector_type(4))) int   i32x4;
typedef __attribute__((ext_vector_type(8))) int   i32x8;

#define UNIT_SCALE 0x7F7F7F7F   // e8m0 = 127 -> 2^0 = 1.0 in all 4 bytes

// ---------------------------------------------------------------------------
// Kernel 1: L2-normalize rows of z1,z2; quantize to OCP fp8 e4m3:
//   h1q = fp8(SCALE * h1_norm)   (A side, pre-scaled so exp2(acc) is direct)
//   h2q = fp8(h2_norm)           (B side)
// exact fp32 diag logits diag5[i] = 5 * cos(z1_i, z2_i); zero rowsum.
// ---------------------------------------------------------------------------
__global__ __launch_bounds__(256) void prep_kernel(
    const float* __restrict__ z1, const float* __restrict__ z2,
    unsigned char* __restrict__ h1q, unsigned char* __restrict__ h2q,
    float* __restrict__ diag5, float* __restrict__ rowsum) {
  int tid = threadIdx.x;
  int w = tid >> 6, lane = tid & 63;
  int r = blockIdx.x * 4 + w;

  const float4 a = ((const float4*)z1)[r * 64 + lane];
  const float4 b = ((const float4*)z2)[r * 64 + lane];

  float ss1 = a.x * a.x + a.y * a.y + a.z * a.z + a.w * a.w;
  float ss2 = b.x * b.x + b.y * b.y + b.z * b.z + b.w * b.w;
  float dp  = a.x * b.x + a.y * b.y + a.z * b.z + a.w * b.w;
  #pragma unroll
  for (int m = 1; m <= 32; m <<= 1) {
    ss1 += __shfl_xor(ss1, m);
    ss2 += __shfl_xor(ss2, m);
    dp  += __shfl_xor(dp, m);
  }
  float inv1 = 1.0f / fmaxf(sqrtf(ss1), 1e-12f);
  float inv2 = 1.0f / fmaxf(sqrtf(ss2), 1e-12f);
  float s1 = inv1 * SCALE;         // fold 1/tau*log2e into A

  int p1 = __builtin_amdgcn_cvt_pk_fp8_f32(a.x * s1, a.y * s1, 0, false);
  p1     = __builtin_amdgcn_cvt_pk_fp8_f32(a.z * s1, a.w * s1, p1, true);
  int p2 = __builtin_amdgcn_cvt_pk_fp8_f32(b.x * inv2, b.y * inv2, 0, false);
  p2     = __builtin_amdgcn_cvt_pk_fp8_f32(b.z * inv2, b.w * inv2, p2, true);
  ((int*)h1q)[r * 64 + lane] = p1;
  ((int*)h2q)[r * 64 + lane] = p2;

  if (lane == 0) diag5[r] = dp * inv1 * inv2 * 5.0f;
  if (tid < 4) rowsum[blockIdx.x * 4 + tid] = 0.0f;  // 4096 blocks * 4 = 16384
}

// ---------------------------------------------------------------------------
// Kernel 2: rowsum_i = sum_j exp2(h1q_i . h2q_j) via MX-scaled fp8 MFMA
// (mfma_scale_f32_16x16x128_f8f6f4, unit e8m0 scales -> exact fp8 matmul at
// 2x the bf16 rate: ~8.6 cyc / 65536-FLOP instr -> 29.5us/CU floor).
// Block = 256 thr (4 waves), Mw=64 rows/wave -> BM=256 rows/block.
// 16-way column split -> grid = 1024 blocks = 4 blocks/CU (LDS 4*32KB=128,
// VGPR<=128 -> 16 waves/CU). Per CU per j-tile: MFMA 4424 cyc (binding),
// LDS 2048, exp2 1024/SIMD, VALU ~1500 -> MFMA-bound with 2x headroom.
// A-frags afr[4][2] i32x8 = 64 VGPR resident (no remat: demand ~115 < 128).
// h2q tiles (64 cols x 256 k fp8 = 16KB) double-buffered via
// global_load_lds(width=16), XOR-swizzled source + same XOR on read.
// Lane layout (x128 fp8): row/col = lane&15, k = (lane>>4)*32..+31 per
// 128-k step; C/D layout is the standard 16x16 (shape-determined).
// ---------------------------------------------------------------------------
#define CSPL 16
#define BN   64
#define NJT  ((NROWS / CSPL) / BN)   // 16 j-tiles per block

__global__ __launch_bounds__(256) void simexp_kernel(
    const unsigned char* __restrict__ h1q, const unsigned char* __restrict__ h2q,
    float* __restrict__ rowsum) {
  __shared__ alignas(16) unsigned char lds[2][BN * DDIM];   // 2 x 16 KB

  int tid = threadIdx.x, w = tid >> 6, lane = tid & 63;
  int bx = blockIdx.x;
  int rb = bx >> 4;        // row block 0..63 (256 rows each)
  int cs = bx & 15;        // column split 0..15 (cs, cs+8 share an XCD L2)
  int row0 = rb * 256 + w * 64;
  int c0 = cs * (NROWS / CSPL);

  const char* h1b = (const char*)h1q;
  const char* h2b = (const char*)h2q;

  // A fragments: 4 row-subtiles x 2 k128-steps, 32 fp8 each -> 64 VGPRs
  i32x8 afr[4][2];
  #pragma unroll
  for (int m = 0; m < 4; ++m)
    #pragma unroll
    for (int ks = 0; ks < 2; ++ks) {
      int row = row0 + m * 16 + (lane & 15);
      int off = row * 256 + ks * 128 + (lane >> 4) * 32;   // 32B aligned
      afr[m][ks] = *reinterpret_cast<const i32x8*>(h1b + off);
    }
  #pragma unroll
  for (int m = 0; m < 4; ++m)
    #pragma unroll
    for (int ks = 0; ks < 2; ++ks)
      asm volatile("" : "+v"(afr[m][ks]));   // keep resident

  float rs[4][4];
  #pragma unroll
  for (int m = 0; m < 4; ++m)
    #pragma unroll
    for (int r = 0; r < 4; ++r) rs[m][r] = 0.0f;

  // stage one 64x256 fp8 h2 tile (16 KB): wave w stages rows w*16..w*16+15
  auto stage = [&](int buf, int jt) {
    int j0 = c0 + jt * BN;
    int rbase = w * 16;
    #pragma unroll
    for (int i = 0; i < 4; ++i) {
      int rit = rbase + i * 4 + (lane >> 4);         // row in tile 0..63
      int kb  = (lane & 15) * 16;                    // byte offset in row
      int src = (j0 + rit) * 256 + (kb ^ ((rit & 7) << 4));  // pre-swizzled src
      __builtin_amdgcn_global_load_lds(
          (const __attribute__((address_space(1))) void*)(h2b + src),
          (__attribute__((address_space(3))) void*)&lds[buf][(rbase + i * 4) * DDIM],
          16, 0, 0);
    }
  };

  stage(0, 0);
  __syncthreads();

  for (int jt = 0; jt < NJT; ++jt) {
    int cur = jt & 1;
    if (jt + 1 < NJT) stage(cur ^ 1, jt + 1);

    const char* L = (const char*)lds[cur];
    for (int n = 0; n < 4; ++n) {
      f32x4 acc[4];
      #pragma unroll
      for (int m = 0; m < 4; ++m) acc[m] = (f32x4){0.f, 0.f, 0.f, 0.f};

      #pragma unroll
      for (int ks = 0; ks < 2; ++ks) {
        int row = n * 16 + (lane & 15);
        int sw  = (row & 7) << 4;
        int base = row * 256 + ks * 128 + (lane >> 4) * 32;
        i32x4 lo = *reinterpret_cast<const i32x4*>(L + (base ^ sw));
        i32x4 hi = *reinterpret_cast<const i32x4*>(L + ((base + 16) ^ sw));
        union { i32x8 v; i32x4 h[2]; } u;
        u.h[0] = lo; u.h[1] = hi;
        #pragma unroll
        for (int m = 0; m < 4; ++m)
          acc[m] = __builtin_amdgcn_mfma_scale_f32_16x16x128_f8f6f4(
              afr[m][ks], u.v, acc[m],
              0 /*cbsz: A=fp8*/, 0 /*blgp: B=fp8*/,
              0, UNIT_SCALE, 0, UNIT_SCALE);
      }
      // A was pre-scaled by (1/tau)*log2e -> rowsum term = exp2(acc) directly
      #pragma unroll
      for (int m = 0; m < 4; ++m)
        #pragma unroll
        for (int r = 0; r < 4; ++r)
          rs[m][r] += __builtin_amdgcn_exp2f(acc[m][r]);
    }
    __syncthreads();
  }

  // reduce the 16 column-lanes (lane&15) and add to global rowsum
  #pragma unroll
  for (int m = 0; m < 4; ++m)
    #pragma unroll
    for (int r = 0; r < 4; ++r) {
      float v = rs[m][r];
      v += __shfl_xor(v, 1);
      v += __shfl_xor(v, 2);
      v += __shfl_xor(v, 4);
      v += __shfl_xor(v, 8);
      if ((lane & 15) == 0)
        atomicAdd(&rowsum[row0 + m * 16 + (lane >> 4) * 4 + r], v);
    }
}

// ---------------------------------------------------------------------------
// Kernel 3: loss = sum_i [ log(rowsum_i - exp(diag5_i)) - diag5_i ]
// ---------------------------------------------------------------------------
__global__ __launch_bounds__(1024) void loss_kernel(
    const float* __restrict__ rowsum, const float* __restrict__ diag5,
    float* __restrict__ out) {
  int tid = threadIdx.x;
  float s = 0.0f;
  for (int i = tid; i < NROWS; i += 1024) {
    float d5 = diag5[i];
    float de = __builtin_amdgcn_exp2f(d5 * LOG2E);
    s += logf(rowsum[i] - de) - d5;
  }
  #pragma unroll
  for (int m = 1; m <= 32; m <<= 1) s += __shfl_xor(s, m);
  __shared__ float wsum[16];
  if ((tid & 63) == 0) wsum[tid >> 6] = s;
  __syncthreads();
  if (tid == 0) {
    float t = 0.0f;
    #pragma unroll
    for (int i = 0; i < 16; ++i) t += wsum[i];
    out[0] = t;
  }
}

// ---------------------------------------------------------------------------
extern "C" void kernel_launch(void* const* d_in, const int* in_sizes, int n_in,
                              void* d_out, int out_size, void* d_ws, size_t ws_size,
                              hipStream_t stream) {
  const float* z1 = (const float*)d_in[0];
  const float* z2 = (const float*)d_in[1];

  char* ws = (char*)d_ws;
  unsigned char* h1q = (unsigned char*)(ws);             // 16384*256 = 4 MB
  unsigned char* h2q = (unsigned char*)(ws + 4194304);   // 4 MB
  float* diag5 = (float*)(ws + 8388608);                 // 64 KB
  float* rowsm = (float*)(ws + 8454144);                 // 64 KB
  if (ws_size < 8519680) return;                         // fail loudly

  prep_kernel<<<4096, 256, 0, stream>>>(z1, z2, h1q, h2q, diag5, rowsm);
  simexp_kernel<<<1024, 256, 0, stream>>>(h1q, h2q, rowsm);
  loss_kernel<<<1, 1024, 0, stream>>>(rowsm, diag5, (float*)d_out);
}